// Round 9
// baseline (248.253 us; speedup 1.0000x reference)
//
#include <hip/hip_runtime.h>
#include <stdint.h>
#include <stddef.h>

// Problem geometry
#define BROWS  16384
#define SROWS  8192
#define FDIM   512
#define NCHUNK 4
#define SCHUNK (SROWS / NCHUNK)     // 2048
#define BM     256                  // X rows per block
#define BN     256                  // S cols per S-tile
#define BK     64                   // K per staged chunk
#define NSTILE (SCHUNK / BN)        // 8
#define NKC    (FDIM / BK)          // 8
#define NC     (NSTILE * NKC)       // 64 chunks per block

#define LOG2E 1.44269504088896340736f

typedef __bf16 bf16x8 __attribute__((ext_vector_type(8)));
typedef float  f32x4  __attribute__((ext_vector_type(4)));

__device__ inline void gload16(const void* g, void* l) {
  __builtin_amdgcn_global_load_lds(
      (const __attribute__((address_space(1))) void*)g,
      (__attribute__((address_space(3))) void*)l, 16, 0, 0);
}

// ---------------------------------------------------------------------------
// Prep S: f32 -> bf16, lc2[s] = log2(coeff[s]) - g*log2e*||s||^2  (validated)
// ---------------------------------------------------------------------------
__global__ __launch_bounds__(256) void prep_s_kernel(
    const float* __restrict__ S, const float* __restrict__ coeff,
    const float* __restrict__ gamma, __bf16* __restrict__ Sb,
    float* __restrict__ lc2)
{
  const int lane = threadIdx.x & 63;
  const int wid  = threadIdx.x >> 6;
  const int row  = (blockIdx.x << 2) + wid;
  const float* src = S + ((size_t)row << 9) + (lane << 3);
  float4 a = ((const float4*)src)[0];
  float4 b = ((const float4*)src)[1];
  float sq = a.x*a.x + a.y*a.y + a.z*a.z + a.w*a.w +
             b.x*b.x + b.y*b.y + b.z*b.z + b.w*b.w;
  bf16x8 v;
  v[0]=(__bf16)a.x; v[1]=(__bf16)a.y; v[2]=(__bf16)a.z; v[3]=(__bf16)a.w;
  v[4]=(__bf16)b.x; v[5]=(__bf16)b.y; v[6]=(__bf16)b.z; v[7]=(__bf16)b.w;
  *(bf16x8*)(Sb + ((size_t)row << 9) + (lane << 3)) = v;
  #pragma unroll
  for (int m = 1; m < 64; m <<= 1) sq += __shfl_xor(sq, m, 64);
  if (lane == 0) lc2[row] = log2f(coeff[row]) - gamma[0] * LOG2E * sq;
}

// ---------------------------------------------------------------------------
// Prep X: f32 -> bf16, ex[row] = exp2(-g*log2e*||x||^2)
// ---------------------------------------------------------------------------
__global__ __launch_bounds__(256) void prep_x_kernel(
    const float* __restrict__ X, const float* __restrict__ gamma,
    __bf16* __restrict__ Xb, float* __restrict__ ex)
{
  const int lane = threadIdx.x & 63;
  const int wid  = threadIdx.x >> 6;
  const int row  = (blockIdx.x << 2) + wid;
  const float* src = X + ((size_t)row << 9) + (lane << 3);
  float4 a = ((const float4*)src)[0];
  float4 b = ((const float4*)src)[1];
  float sq = a.x*a.x + a.y*a.y + a.z*a.z + a.w*a.w +
             b.x*b.x + b.y*b.y + b.z*b.z + b.w*b.w;
  bf16x8 v;
  v[0]=(__bf16)a.x; v[1]=(__bf16)a.y; v[2]=(__bf16)a.z; v[3]=(__bf16)a.w;
  v[4]=(__bf16)b.x; v[5]=(__bf16)b.y; v[6]=(__bf16)b.z; v[7]=(__bf16)b.w;
  *(bf16x8*)(Xb + ((size_t)row << 9) + (lane << 3)) = v;
  #pragma unroll
  for (int m = 1; m < 64; m <<= 1) sq += __shfl_xor(sq, m, 64);
  if (lane == 0) ex[row] = exp2f(-gamma[0] * LOG2E * sq);
}

// ---------------------------------------------------------------------------
// Main: 2D register-blocked fused RBF-GEMM.
// Block 512 thr = 8 waves (2M x 4N); wave computes 128x64 via 16x16x32 MFMA
// (M_rep=8, N_rep=4). A(X) and B(S) tiles both staged in LDS, double-buffered
// (2 x 64 KB). LDS layout per tile: [row(256)][64k: 128 B] with XOR swizzle
// byte^=((row&7)<<4) applied on the GLOBAL SOURCE (gload_lds dest stays
// linear) and on the ds_read address -> bank-balanced b128 frag reads.
// Per K-chunk: vmcnt(0) [cheap: loads issued one full chunk earlier] ->
// barrier -> STAGE(next chunk) [post-barrier => dbuf race-free] -> compute.
// Per S-tile epilogue: score += exp2(K2*cross + lc2[col]); final lane-reduce
// over 16 cols -> per-(chunk,wn) partials.
// ---------------------------------------------------------------------------
__global__ __launch_bounds__(512, 2) void ocsvm_main_kernel(
    const __bf16* __restrict__ Xb, const __bf16* __restrict__ Sb,
    const float* __restrict__ lc2, const float* __restrict__ ex,
    const float* __restrict__ gamma, float* __restrict__ partials)
{
  __shared__ char lds[131072];   // 2 x (A 32 KB + B 32 KB)
  const int tid  = threadIdx.x;
  const int lane = tid & 63;
  const int wid  = tid >> 6;
  const int wm   = wid >> 2;        // 0..1  (M group: 128 rows)
  const int wn   = wid & 3;         // 0..3  (N group: 64 cols)
  const int lr   = lane & 15;
  const int hi   = lane >> 4;

  // XCD-affine: blocks on one XCD share one S-chunk
  const int bx      = blockIdx.x;
  const int xcd     = bx & 7;
  const int grp     = bx >> 3;
  const int chunkid = xcd >> 1;
  const int mtile   = (grp << 1) + (xcd & 1);
  const int m0      = mtile * BM;
  const int chunk0  = chunkid * SCHUNK;

  const float K2 = 2.0f * gamma[0] * LOG2E;

  const char* xb = (const char*)Xb;
  const char* sb = (const char*)Sb;
  const int r0     = tid >> 3;                      // staging row 0..63
  const int srcoff = ((tid & 7) << 4) ^ ((r0 & 7) << 4);  // pre-swizzled src col-byte

  // stage one K-chunk: A 32 KB + B 32 KB, 8 x gload16 per thread, linear dst
#define STAGE(bufsel, c)                                                      \
  { const int st_ = (c) >> 3, kc_ = (c) & 7;                                  \
    const char* asrc_ = xb + (((size_t)(m0 + r0)) << 10) + (kc_ << 7) + srcoff; \
    const char* bsrc_ = sb + (((size_t)(chunk0 + (st_ << 8) + r0)) << 10)     \
                           + (kc_ << 7) + srcoff;                             \
    char* ad_ = &lds[(bufsel) * 65536 + (tid << 4)];                          \
    _Pragma("unroll")                                                         \
    for (int j = 0; j < 4; ++j) {                                             \
      gload16(asrc_ + j * 65536, ad_ + j * 8192);                             \
      gload16(bsrc_ + j * 65536, ad_ + 32768 + j * 8192);                     \
    } }

  // frag-read swizzled k-offsets (bits 4-6): (ks*64 + hi*16) ^ ((lr&7)<<4)
  const int sw0 = (hi << 4) ^ ((lr & 7) << 4);
  const int sw1 = sw0 ^ 64;

  float score[8][4];
  #pragma unroll
  for (int mi = 0; mi < 8; ++mi)
    #pragma unroll
    for (int j = 0; j < 4; ++j) score[mi][j] = 0.0f;

  STAGE(0, 0);   // prologue

  int c = 0;
  for (int st = 0; st < NSTILE; ++st) {
    f32x4 acc[8][4];
    #pragma unroll
    for (int mi = 0; mi < 8; ++mi)
      #pragma unroll
      for (int ni = 0; ni < 4; ++ni) acc[mi][ni] = (f32x4){0.f, 0.f, 0.f, 0.f};

    for (int kc = 0; kc < NKC; ++kc, ++c) {
      // own buf-c loads were issued one full chunk ago -> vmcnt(0) is cheap
      asm volatile("s_waitcnt vmcnt(0)" ::: "memory");
      __builtin_amdgcn_s_barrier();
      asm volatile("" ::: "memory");
      if (c + 1 < NC) STAGE((c + 1) & 1, c + 1);   // post-barrier: dbuf-safe

      const char* bA = &lds[(c & 1) * 65536 + wm * 16384 + lr * 128];
      const char* bB = &lds[(c & 1) * 65536 + 32768 + (wn << 13) + lr * 128];

      #pragma unroll
      for (int ks = 0; ks < 2; ++ks) {
        const int swk = ks ? sw1 : sw0;
        bf16x8 bfr[4], af[8];
        #pragma unroll
        for (int ni = 0; ni < 4; ++ni)
          bfr[ni] = *(const bf16x8*)(bB + swk + ni * 2048);
        #pragma unroll
        for (int mi = 0; mi < 8; ++mi)
          af[mi] = *(const bf16x8*)(bA + swk + mi * 2048);
        #pragma unroll
        for (int mi = 0; mi < 8; ++mi)
          #pragma unroll
          for (int ni = 0; ni < 4; ++ni)
            acc[mi][ni] = __builtin_amdgcn_mfma_f32_16x16x32_bf16(
                af[mi], bfr[ni], acc[mi][ni], 0, 0, 0);
      }
    }

    // epilogue for S-tile st: cols = chunk0 + st*256 + wn*64 + ni*16 + lr
    const float* lc = lc2 + chunk0 + (st << 8) + (wn << 6) + lr;
    const float l0 = lc[0], l1 = lc[16], l2 = lc[32], l3 = lc[48];
    #pragma unroll
    for (int mi = 0; mi < 8; ++mi)
      #pragma unroll
      for (int j = 0; j < 4; ++j)
        score[mi][j] += __builtin_amdgcn_exp2f(__builtin_fmaf(K2, acc[mi][0][j], l0))
                      + __builtin_amdgcn_exp2f(__builtin_fmaf(K2, acc[mi][1][j], l1))
                      + __builtin_amdgcn_exp2f(__builtin_fmaf(K2, acc[mi][2][j], l2))
                      + __builtin_amdgcn_exp2f(__builtin_fmaf(K2, acc[mi][3][j], l3));
  }

  // fold 16 col-lanes, scale by e_x, write per-(chunk,wn) partial
  // C layout (m89): col = lane&15, row = (lane>>4)*4 + reg
  #pragma unroll
  for (int mi = 0; mi < 8; ++mi)
    #pragma unroll
    for (int j = 0; j < 4; ++j) {
      float v = score[mi][j];
      v += __shfl_xor(v, 1, 64);
      v += __shfl_xor(v, 2, 64);
      v += __shfl_xor(v, 4, 64);
      v += __shfl_xor(v, 8, 64);
      const int row = m0 + (wm << 7) + (mi << 4) + (hi << 2) + j;
      if (lr == 0)
        partials[(size_t)((chunkid << 2) + wn) * BROWS + row] = ex[row] * v;
    }
#undef STAGE
}

// ---------------------------------------------------------------------------
// Final: sum 16 partial slices (4 chunks x 4 wn), subtract rho.
// ---------------------------------------------------------------------------
__global__ __launch_bounds__(256) void reduce_kernel(
    const float* __restrict__ partials, const float* __restrict__ rho,
    float* __restrict__ out)
{
  const int i = blockIdx.x * 256 + threadIdx.x;
  float s = 0.0f;
  #pragma unroll
  for (int k = 0; k < 16; ++k) s += partials[(size_t)k * BROWS + i];
  out[i] = s - rho[0];
}

extern "C" void kernel_launch(void* const* d_in, const int* in_sizes, int n_in,
                              void* d_out, int out_size, void* d_ws, size_t ws_size,
                              hipStream_t stream) {
  const float* X     = (const float*)d_in[0];   // [16384,512] f32
  const float* S     = (const float*)d_in[1];   // [8192,512]  f32
  const float* coeff = (const float*)d_in[2];   // [1,8192]    f32
  const float* rho   = (const float*)d_in[3];   // [1]         f32
  const float* gamma = (const float*)d_in[4];   // scalar      f32
  float* out = (float*)d_out;

  // ws: Sb 8MB | Xb 16MB | lc2 32KB | ex 64KB | partials 1MB  (~25.1 MB)
  char* ws = (char*)d_ws;
  __bf16* Sb    = (__bf16*)ws;
  __bf16* Xbuf  = (__bf16*)(ws + ((size_t)SROWS * FDIM * 2));
  float*  lc2   = (float*)(ws + ((size_t)SROWS * FDIM * 2) + ((size_t)BROWS * FDIM * 2));
  float*  ex    = lc2 + SROWS;
  float*  parts = ex + BROWS;

  prep_s_kernel<<<SROWS / 4, 256, 0, stream>>>(S, coeff, gamma, Sb, lc2);
  prep_x_kernel<<<BROWS / 4, 256, 0, stream>>>(X, gamma, Xbuf, ex);
  ocsvm_main_kernel<<<NCHUNK * 64, 512, 0, stream>>>(Xbuf, Sb, lc2, ex, gamma, parts);
  reduce_kernel<<<BROWS / 256, 256, 0, stream>>>(parts, rho, out);
}